// Round 13
// baseline (42.715 us; speedup 1.0000x reference)
//
#include <hip/hip_runtime.h>
#include <hip/hip_bf16.h>

#define BSZ 4096
#define NSZ 8192
#define DD  128
#define GROUPS 8
#define TPB 8     // 128-col tiles per block

typedef __attribute__((ext_vector_type(8))) short bf16x8;
typedef __attribute__((ext_vector_type(4))) float f32x4;

typedef __attribute__((address_space(3))) unsigned int lds_u32;
typedef const __attribute__((address_space(1))) unsigned int glb_u32;

// ---------------- Kernel 1: normalize rows of reps=[zjs; zis] -> bf16 ----------------
__global__ __launch_bounds__(256)
void norm_kernel(const float* __restrict__ zis,
                 const float* __restrict__ zjs,
                 __hip_bfloat16* __restrict__ rn) {
    const int row  = blockIdx.x * 4 + (threadIdx.x >> 6);
    const int lane = threadIdx.x & 63;
    const float* src = (row < BSZ) ? (zjs + (size_t)row * DD)
                                   : (zis + (size_t)(row - BSZ) * DD);
    float2 v = *(const float2*)(src + lane * 2);
    float ss = v.x * v.x + v.y * v.y;
    #pragma unroll
    for (int off = 32; off; off >>= 1) ss += __shfl_xor(ss, off);
    float inv = 1.0f / fmaxf(sqrtf(ss), 1e-8f);
    __hip_bfloat16 a = __float2bfloat16(v.x * inv);
    __hip_bfloat16 b = __float2bfloat16(v.y * inv);
    ushort2 pk;
    pk.x = *(const ushort*)&a;
    pk.y = *(const ushort*)&b;
    *(ushort2*)(rn + (size_t)row * DD + lane * 2) = pk;
}

// ---------------- Kernel 2: fat-tile LDS GEMM + exp + row sums ----------------------
// grid (GROUPS=8, 32): bi = blockIdx.y (256-row tile), g = blockIdx.x. Block loops
// over TPB=8 col-tiles of 128 (bj = g*8+t). 512 threads = 8 waves (wm 0..3 x wn 0..1),
// wave tile 64x64 -> 8 B LDS traffic per output (vs 12 at 32x64): LDS-pipe floor
// ~10.3 us/CU. A-tile 64KB staged once; B dbuf 2x32KB (stage issued before compute,
// latency hidden). 128KB LDS -> 1 block/CU, grid = exactly 1 block/CU.
// waves_per_eu(2,2): max occupancy 2 waves/EU regardless, so the allocator has no
// incentive to clamp VGPRs at 128 and spill (the R10 failure). Operands ds_read
// per kk (8-reg lifetime). Row sums in regs across all tiles; direct stores.
__global__ __launch_bounds__(512) __attribute__((amdgpu_waves_per_eu(2, 2)))
void sim_lse_kernel(const __hip_bfloat16* __restrict__ rn,
                    float* __restrict__ partials,   // [16][NSZ]
                    float* __restrict__ pos) {
    __shared__ ushort As[256 * DD];      // 64 KB
    __shared__ ushort Bt[2][128 * DD];   // 2 x 32 KB

    const int g   = blockIdx.x;
    const int bi  = blockIdx.y;          // 0..31 (256-row tiles)
    const int tid = threadIdx.x;
    const int wid  = tid >> 6;           // 0..7
    const int lane = tid & 63;
    const int l15  = lane & 15;
    const int kg   = lane >> 4;          // 0..3
    const int wm   = wid >> 1;           // 0..3 (64-row quarter)
    const int wn   = wid & 1;            // 0..1 (64-col half)

    // ---- stage A tile (64KB, once) + B tile 0; linear dest, pre-swizzled source ----
    {
        const char* ga = (const char*)rn + (size_t)bi * 256 * 256;
        #pragma unroll
        for (int j = 0; j < 8; ++j) {
            int cs  = (wid * 8 + j) * 64 + lane;     // chunk (16B units), 0..4095
            int gsc = cs ^ ((cs >> 4) & 7);
            __builtin_amdgcn_global_load_lds((glb_u32*)(ga + (size_t)gsc * 16),
                                             (lds_u32*)(As + (wid * 8 + j) * 512),
                                             16, 0, 0);
        }
        const char* gb = (const char*)rn + (size_t)(g * TPB) * 128 * 256;
        #pragma unroll
        for (int j = 0; j < 4; ++j) {
            int cs  = (wid * 4 + j) * 64 + lane;     // 0..2047
            int gsc = cs ^ ((cs >> 4) & 7);
            __builtin_amdgcn_global_load_lds((glb_u32*)(gb + (size_t)gsc * 16),
                                             (lds_u32*)(&Bt[0][0] + (wid * 4 + j) * 512),
                                             16, 0, 0);
        }
    }
    __syncthreads();   // vmcnt(0) drain: As + Bt[0] ready

    float rsum[4][4] = {};
    const int ru = bi * 4 + wm;          // row base in 64-units, 0..127
    const int pu = (ru + 64) & 127;      // partner col unit
    const char* Ab = (const char*)As;

    for (int t = 0; t < TPB; ++t) {
        const int bj = g * TPB + t;

        // ---- issue next B stage first (hides under this tile's compute) ----
        if (t + 1 < TPB) {
            const char* gb = (const char*)rn + (size_t)(bj + 1) * 128 * 256;
            ushort* dst = &Bt[(t + 1) & 1][0];
            #pragma unroll
            for (int j = 0; j < 4; ++j) {
                int cs  = (wid * 4 + j) * 64 + lane;
                int gsc = cs ^ ((cs >> 4) & 7);
                __builtin_amdgcn_global_load_lds((glb_u32*)(gb + (size_t)gsc * 16),
                                                 (lds_u32*)(dst + (wid * 4 + j) * 512),
                                                 16, 0, 0);
            }
        }

        // ---- MFMA: 64 rows x 64 cols per wave, K=128; operands ds_read per kk ----
        f32x4 acc[4][4] = {};
        const char* Bb = (const char*)&Bt[t & 1][0];
        #pragma unroll
        for (int kk = 0; kk < 4; ++kk) {
            const int kb = kk * 64 + kg * 16;
            bf16x8 afr[4];
            #pragma unroll
            for (int mf = 0; mf < 4; ++mf) {
                int rR = wm * 64 + mf * 16 + l15;
                int o = rR * 256 + kb;
                afr[mf] = *(const bf16x8*)(Ab + (o ^ ((rR & 7) << 4)));
            }
            bf16x8 bfr[4];
            #pragma unroll
            for (int nf = 0; nf < 4; ++nf) {
                int cR = wn * 64 + nf * 16 + l15;
                int o = cR * 256 + kb;
                bfr[nf] = *(const bf16x8*)(Bb + (o ^ ((cR & 7) << 4)));
            }
            #pragma unroll
            for (int mf = 0; mf < 4; ++mf)
                #pragma unroll
                for (int nf = 0; nf < 4; ++nf)
                    acc[mf][nf] = __builtin_amdgcn_mfma_f32_16x16x32_bf16(
                        afr[mf], bfr[nf], acc[mf][nf], 0, 0, 0);
        }

        // ---- epilogue: exp + rsum accumulate; wave-uniform rare fixups ----
        const int cu = bj * 2 + wn;      // col base in 64-units, 0..127
        const bool dglb = (cu == ru);
        const bool pglb = (cu == pu);
        #pragma unroll
        for (int mf = 0; mf < 4; ++mf) {
            #pragma unroll
            for (int nf = 0; nf < 4; ++nf) {
                #pragma unroll
                for (int reg = 0; reg < 4; ++reg) {
                    float s = acc[mf][nf][reg];
                    bool hit = (mf == nf) && (kg * 4 + reg == l15);
                    if (pglb && hit)
                        pos[ru * 64 + mf * 16 + l15] = s;
                    float p = __expf(s * 10.0f);
                    if (dglb && hit) p = 0.0f;
                    rsum[mf][reg] += p;
                }
            }
        }

        __syncthreads();   // vmcnt(0) drain (next B staged) + protects buffers
    }

    // ---- row-sum reduce across the 16 l15-lanes; direct store (disjoint slabs) ----
    #pragma unroll
    for (int mf = 0; mf < 4; ++mf)
        #pragma unroll
        for (int reg = 0; reg < 4; ++reg) {
            float v = rsum[mf][reg];
            v += __shfl_xor(v, 1);
            v += __shfl_xor(v, 2);
            v += __shfl_xor(v, 4);
            v += __shfl_xor(v, 8);
            if (l15 == 0)
                partials[(size_t)(g * 2 + wn) * NSZ
                         + ru * 64 + mf * 16 + kg * 4 + reg] = v;
        }
}

// ---------------- Kernel 3: final scalar reduction over 16 slabs ----------------
__global__ __launch_bounds__(1024)
void reduce_kernel(const float* __restrict__ partials,
                   const float* __restrict__ pos,
                   float* __restrict__ out) {
    int tid = threadIdx.x;  // 1024; 8 rows each
    int base = tid * 8;
    float se[8] = {0.f, 0.f, 0.f, 0.f, 0.f, 0.f, 0.f, 0.f};
    #pragma unroll
    for (int gr = 0; gr < 2 * GROUPS; ++gr) {
        const float* p = partials + (size_t)gr * NSZ + base;
        float4 a = *(const float4*)(p);
        float4 b = *(const float4*)(p + 4);
        se[0] += a.x; se[1] += a.y; se[2] += a.z; se[3] += a.w;
        se[4] += b.x; se[5] += b.y; se[6] += b.z; se[7] += b.w;
    }
    float ce = 0.f, pt = 0.f;
    #pragma unroll
    for (int h = 0; h < 2; ++h) {
        float4 p4 = *(const float4*)(pos + base + h * 4);
        const float* pp = (const float*)&p4;
        #pragma unroll
        for (int q = 0; q < 4; ++q) {
            float s = se[h * 4 + q];
            ce += __logf(s) - pp[q] * 10.0f;
            pt += __expf(pp[q] * 10.0f) / s;
        }
    }
    #pragma unroll
    for (int off = 32; off; off >>= 1) {
        ce += __shfl_xor(ce, off);
        pt += __shfl_xor(pt, off);
    }
    __shared__ float lce[16], lpt[16];
    if ((tid & 63) == 0) { lce[tid >> 6] = ce; lpt[tid >> 6] = pt; }
    __syncthreads();
    if (tid == 0) {
        float CE = 0.f, PT = 0.f;
        #pragma unroll
        for (int w = 0; w < 16; ++w) { CE += lce[w]; PT += lpt[w]; }
        float loss = CE / (float)NSZ + 1.0f
                   - PT * ((float)BSZ / ((float)NSZ * (float)(NSZ - 1)));
        out[0] = loss;
    }
}

extern "C" void kernel_launch(void* const* d_in, const int* in_sizes, int n_in,
                              void* d_out, int out_size, void* d_ws, size_t ws_size,
                              hipStream_t stream) {
    const float* zis = (const float*)d_in[0];
    const float* zjs = (const float*)d_in[1];
    float* out = (float*)d_out;

    char* ws = (char*)d_ws;
    __hip_bfloat16* rn = (__hip_bfloat16*)ws;                       // 2 MB
    float* partials = (float*)(ws + 2 * 1024 * 1024);               // 512 KB
    float* pos      = (float*)(ws + 2 * 1024 * 1024 + 512 * 1024);  // 32 KB

    norm_kernel<<<NSZ / 4, 256, 0, stream>>>(zis, zjs, rn);

    dim3 grid(GROUPS, 32);
    sim_lse_kernel<<<grid, 512, 0, stream>>>(rn, partials, pos);

    reduce_kernel<<<1, 1024, 0, stream>>>(partials, pos, out);
}